// Round 1
// baseline (782.482 us; speedup 1.0000x reference)
//
#include <hip/hip_runtime.h>

#define N_NODES 100000
#define N_EDGES 3200000
#define NFEAT 256
#define HID 32
#define NCLASS 16

// ---------------- degree / norm ----------------

__global__ void k_init_deg(float* __restrict__ deg) {
    int i = blockIdx.x * 256 + threadIdx.x;
    if (i < N_NODES) deg[i] = 1.0f;  // self-loop weight
}

__global__ void k_accum_deg(const int* __restrict__ col, const float* __restrict__ w,
                            float* __restrict__ deg) {
    int e = blockIdx.x * 256 + threadIdx.x;
    if (e < N_EDGES) atomicAdd(&deg[col[e]], w[e]);
}

__global__ void k_finish_dinv(float* __restrict__ deg) {
    int i = blockIdx.x * 256 + threadIdx.x;
    if (i < N_NODES) {
        float d = deg[i];
        deg[i] = (d > 0.0f) ? rsqrtf(d) : 0.0f;
    }
}

// ---------------- GEMM 1: xw = x @ W1  [N,256]x[256,32] ----------------
// 8 rows per block of 256 threads; W1 (32KB) + 8 x-rows (8KB) in LDS.
__global__ __launch_bounds__(256) void k_gemm1(const float* __restrict__ x,
                                               const float* __restrict__ W1,
                                               float* __restrict__ xw) {
    __shared__ float sW[NFEAT * HID];   // 8192 floats = 32KB
    __shared__ float sX[8 * NFEAT];     // 2048 floats = 8KB
    int t = threadIdx.x;
    #pragma unroll
    for (int k = 0; k < (NFEAT * HID) / 256; ++k) sW[t + k * 256] = W1[t + k * 256];
    long base = (long)blockIdx.x * 8 * NFEAT;
    #pragma unroll
    for (int i = 0; i < 8; ++i) sX[t + i * 256] = x[base + t + i * 256];
    __syncthreads();
    int r = t >> 5, c = t & 31;
    const float* xr = &sX[r * NFEAT];
    float acc = 0.0f;
    #pragma unroll 8
    for (int k = 0; k < NFEAT; ++k) acc = fmaf(xr[k], sW[k * HID + c], acc);
    xw[(long)blockIdx.x * 8 * HID + r * HID + c] = acc;
}

// ---------------- conv1 aggregation ----------------

__global__ void k_init_agg1(const float* __restrict__ xw, const float* __restrict__ dinv,
                            float* __restrict__ agg) {
    int i = blockIdx.x * 256 + threadIdx.x;  // over N*HID, exact
    int node = i >> 5;
    float di = dinv[node];
    agg[i] = xw[i] * di * di;   // self-loop: norm = dinv*1*dinv
}

__global__ void k_scatter1(const int* __restrict__ row, const int* __restrict__ col,
                           const float* __restrict__ w, const float* __restrict__ dinv,
                           const float* __restrict__ xw, float* __restrict__ agg) {
    int idx = blockIdx.x * 256 + threadIdx.x;
    int e = idx >> 5, c = idx & 31;
    if (e >= N_EDGES) return;
    int r = row[e], cl = col[e];
    float nrm = dinv[r] * w[e] * dinv[cl];
    atomicAdd(&agg[(long)cl * HID + c], xw[(long)r * HID + c] * nrm);
}

__global__ void k_relu_bias(float* __restrict__ h, const float* __restrict__ b1) {
    int i = blockIdx.x * 256 + threadIdx.x;  // over N*HID
    float v = h[i] + b1[i & (HID - 1)];
    h[i] = v > 0.0f ? v : 0.0f;
}

// ---------------- GEMM 2: hw = h @ W2  [N,32]x[32,16] ----------------
__global__ __launch_bounds__(256) void k_gemm2(const float* __restrict__ h,
                                               const float* __restrict__ W2,
                                               float* __restrict__ hw) {
    __shared__ float sW[HID * NCLASS];  // 512
    __shared__ float sH[16 * HID];      // 512
    int t = threadIdx.x;
    #pragma unroll
    for (int i = 0; i < 2; ++i) sW[t + i * 256] = W2[t + i * 256];
    long base = (long)blockIdx.x * 16 * HID;
    #pragma unroll
    for (int i = 0; i < 2; ++i) sH[t + i * 256] = h[base + t + i * 256];
    __syncthreads();
    int r = t >> 4, c = t & 15;
    const float* hr = &sH[r * HID];
    float acc = 0.0f;
    #pragma unroll
    for (int k = 0; k < HID; ++k) acc = fmaf(hr[k], sW[k * NCLASS + c], acc);
    hw[(long)blockIdx.x * 16 * NCLASS + r * NCLASS + c] = acc;
}

// ---------------- conv2 aggregation ----------------

__global__ void k_init_agg2(const float* __restrict__ hw, const float* __restrict__ dinv,
                            float* __restrict__ agg) {
    int i = blockIdx.x * 256 + threadIdx.x;  // over N*NCLASS, exact
    int node = i >> 4;
    float di = dinv[node];
    agg[i] = hw[i] * di * di;
}

__global__ void k_scatter2(const int* __restrict__ row, const int* __restrict__ col,
                           const float* __restrict__ w, const float* __restrict__ dinv,
                           const float* __restrict__ hw, float* __restrict__ agg) {
    int idx = blockIdx.x * 256 + threadIdx.x;
    int e = idx >> 4, c = idx & 15;
    if (e >= N_EDGES) return;
    int r = row[e], cl = col[e];
    float nrm = dinv[r] * w[e] * dinv[cl];
    atomicAdd(&agg[(long)cl * NCLASS + c], hw[(long)r * NCLASS + c] * nrm);
}

// ---------------- bias + log_softmax over 16 classes ----------------
__global__ void k_logsoftmax(const float* __restrict__ agg, const float* __restrict__ b2,
                             float* __restrict__ out) {
    int idx = blockIdx.x * 256 + threadIdx.x;  // over N*NCLASS, exact
    int c = idx & 15;
    float v = agg[idx] + b2[c];
    float m = v;
    #pragma unroll
    for (int d = 1; d < 16; d <<= 1) m = fmaxf(m, __shfl_xor(m, d, 16));
    float s = __expf(v - m);
    #pragma unroll
    for (int d = 1; d < 16; d <<= 1) s += __shfl_xor(s, d, 16);
    out[idx] = v - m - __logf(s);
}

extern "C" void kernel_launch(void* const* d_in, const int* in_sizes, int n_in,
                              void* d_out, int out_size, void* d_ws, size_t ws_size,
                              hipStream_t stream) {
    const float* x  = (const float*)d_in[0];
    const int*   ei = (const int*)d_in[1];          // [2, E] flattened
    const float* w  = (const float*)d_in[2];
    const float* W1 = (const float*)d_in[3];
    // b1 = d_in[4] (zeros, but honor it anyway)
    const float* b1 = (const float*)d_in[4];
    const float* W2 = (const float*)d_in[5];
    const float* b2 = (const float*)d_in[6];
    float* out = (float*)d_out;

    const int* row = ei;             // source
    const int* col = ei + N_EDGES;   // target

    float* ws = (float*)d_ws;
    float* dinv = ws;                                 // N
    float* xw   = dinv + N_NODES;                     // N*32
    float* agg1 = xw + (size_t)N_NODES * HID;         // N*32 (becomes h in place)
    float* hw   = agg1 + (size_t)N_NODES * HID;       // N*16
    float* agg2 = hw + (size_t)N_NODES * NCLASS;      // N*16

    const int B = 256;

    k_init_deg<<<(N_NODES + B - 1) / B, B, 0, stream>>>(dinv);
    k_accum_deg<<<(N_EDGES + B - 1) / B, B, 0, stream>>>(col, w, dinv);
    k_finish_dinv<<<(N_NODES + B - 1) / B, B, 0, stream>>>(dinv);

    k_gemm1<<<N_NODES / 8, B, 0, stream>>>(x, W1, xw);

    k_init_agg1<<<(N_NODES * HID) / B, B, 0, stream>>>(xw, dinv, agg1);
    k_scatter1<<<(int)(((long)N_EDGES * HID + B - 1) / B), B, 0, stream>>>(row, col, w, dinv, xw, agg1);
    k_relu_bias<<<(N_NODES * HID) / B, B, 0, stream>>>(agg1, b1);

    k_gemm2<<<N_NODES / 16, B, 0, stream>>>(agg1, W2, hw);

    k_init_agg2<<<(N_NODES * NCLASS) / B, B, 0, stream>>>(hw, dinv, agg2);
    k_scatter2<<<(int)(((long)N_EDGES * NCLASS + B - 1) / B), B, 0, stream>>>(row, col, w, dinv, hw, agg2);

    k_logsoftmax<<<(N_NODES * NCLASS) / B, B, 0, stream>>>(agg2, b2, out);
}